// Round 1
// baseline (7697.166 us; speedup 1.0000x reference)
//
#include <hip/hip_runtime.h>
#include <hip/hip_bf16.h>
#include <math.h>

// Problem constants (from reference)
#define NLAYER 4
#define NH     8
#define CDIM   512
#define HS     64
#define VOCAB  32000
#define BB     2
#define TT     2048
#define MROWS  (BB*TT)   // 4096

#define BM 64
#define BN 64
#define BK 32

// flags: 1=bias, 2=relu, 4=residual-add-into-C
template<bool BTRANS>
__device__ __forceinline__ void gemm_core(
    const float* __restrict__ A, int lda,        // pre-offset to (m0, 0)
    const float* __restrict__ Bm, int ldb,       // !BTRANS: B pre-offset to (0, n0), ldb = row stride over k
                                                 //  BTRANS: B pre-offset to (n0 row, 0), ldb = row stride over n
    int K, float (&acc)[4][4],
    float (*As)[BM+4], float (*Bs)[BN])
{
    const int tid = threadIdx.x;
    const int tx = tid & 15, ty = tid >> 4;
    for (int k0 = 0; k0 < K; k0 += BK) {
        __syncthreads();
        // A tile: 64 m x 32 k, store transposed As[k][m]
        {
            int mr = tid >> 3;
            int kc = (tid & 7) << 2;
            #pragma unroll
            for (int i = 0; i < 2; i++) {
                int m = mr + i*32;
                float4 av = *(const float4*)(A + (long)m*lda + k0 + kc);
                As[kc+0][m] = av.x; As[kc+1][m] = av.y;
                As[kc+2][m] = av.z; As[kc+3][m] = av.w;
            }
        }
        if (!BTRANS) {
            int kr = tid >> 4;
            int nc = (tid & 15) << 2;
            #pragma unroll
            for (int i = 0; i < 2; i++) {
                int kk = kr + i*16;
                *(float4*)&Bs[kk][nc] = *(const float4*)(Bm + (long)(k0+kk)*ldb + nc);
            }
        } else {
            int nr = tid >> 3;
            int kc = (tid & 7) << 2;
            #pragma unroll
            for (int i = 0; i < 2; i++) {
                int n = nr + i*32;
                float4 bv = *(const float4*)(Bm + (long)n*ldb + k0 + kc);
                Bs[kc+0][n] = bv.x; Bs[kc+1][n] = bv.y;
                Bs[kc+2][n] = bv.z; Bs[kc+3][n] = bv.w;
            }
        }
        __syncthreads();
        #pragma unroll
        for (int kk = 0; kk < BK; kk++) {
            float4 a = *(const float4*)&As[kk][ty*4];
            float4 b = *(const float4*)&Bs[kk][tx*4];
            acc[0][0] += a.x*b.x; acc[0][1] += a.x*b.y; acc[0][2] += a.x*b.z; acc[0][3] += a.x*b.w;
            acc[1][0] += a.y*b.x; acc[1][1] += a.y*b.y; acc[1][2] += a.y*b.z; acc[1][3] += a.y*b.w;
            acc[2][0] += a.z*b.x; acc[2][1] += a.z*b.y; acc[2][2] += a.z*b.z; acc[2][3] += a.z*b.w;
            acc[3][0] += a.w*b.x; acc[3][1] += a.w*b.y; acc[3][2] += a.w*b.z; acc[3][3] += a.w*b.w;
        }
    }
}

__global__ __launch_bounds__(256) void gemm_kernel(
    const float* __restrict__ A, int lda,
    const float* __restrict__ Bm, int ldb, int btrans,
    const float* __restrict__ bias,
    float* __restrict__ Cmat, int ldc,
    int K, int flags)
{
    __shared__ float As[BK][BM+4];
    __shared__ float Bs[BK][BN];
    const long m0 = (long)blockIdx.y * BM;
    const long n0 = (long)blockIdx.x * BN;
    float acc[4][4] = {};
    const float* Ab = A + m0*lda;
    if (btrans) {
        gemm_core<true>(Ab, lda, Bm + n0*ldb, ldb, K, acc, As, Bs);
    } else {
        gemm_core<false>(Ab, lda, Bm + n0, ldb, K, acc, As, Bs);
    }
    const int tx = threadIdx.x & 15, ty = threadIdx.x >> 4;
    float4 b4 = make_float4(0.f, 0.f, 0.f, 0.f);
    if (flags & 1) b4 = *(const float4*)(bias + n0 + tx*4);
    #pragma unroll
    for (int i = 0; i < 4; i++) {
        long m = m0 + ty*4 + i;
        float4 r = make_float4(acc[i][0] + b4.x, acc[i][1] + b4.y,
                               acc[i][2] + b4.z, acc[i][3] + b4.w);
        if (flags & 2) {
            r.x = fmaxf(r.x, 0.f); r.y = fmaxf(r.y, 0.f);
            r.z = fmaxf(r.z, 0.f); r.w = fmaxf(r.w, 0.f);
        }
        float4* cp = (float4*)(Cmat + m*ldc + n0 + tx*4);
        if (flags & 4) {
            float4 old = *cp;
            r.x += old.x; r.y += old.y; r.z += old.z; r.w += old.w;
        }
        *cp = r;
    }
}

// Q/K/V projection: grid (TT/64, NH, 6), z = b*3 + which
__global__ __launch_bounds__(256) void gemm_qkv_kernel(
    const float* __restrict__ hbuf,     // [BB*TT, CDIM]
    const float* __restrict__ wq,       // [NH, CDIM, HS] (this layer)
    const float* __restrict__ wk,
    const float* __restrict__ wv,
    float* __restrict__ qo, float* __restrict__ ko, float* __restrict__ vo)
{
    __shared__ float As[BK][BM+4];
    __shared__ float Bs[BK][BN];
    const int z = blockIdx.z;
    const int b = z / 3, which = z % 3;
    const int hh = blockIdx.y;
    const long m0 = (long)blockIdx.x * BM;   // t-tile within this b
    const float* W = (which == 0 ? wq : which == 1 ? wk : wv) + (long)hh*CDIM*HS;
    const float* Ab = hbuf + ((long)b*TT + m0)*CDIM;
    float* Cb = (which == 0 ? qo : which == 1 ? ko : vo) + ((long)(b*NH + hh)*TT)*HS;
    float acc[4][4] = {};
    gemm_core<false>(Ab, CDIM, W, HS, CDIM, acc, As, Bs);
    const int tx = threadIdx.x & 15, ty = threadIdx.x >> 4;
    #pragma unroll
    for (int i = 0; i < 4; i++) {
        long m = m0 + ty*4 + i;
        float4 r = make_float4(acc[i][0], acc[i][1], acc[i][2], acc[i][3]);
        *(float4*)(Cb + m*HS + tx*4) = r;
    }
}

__global__ void embed_kernel(const int* __restrict__ idx,
                             const float* __restrict__ tok,
                             const float* __restrict__ pos,
                             float* __restrict__ x)
{
    const int r = blockIdx.x;
    const int t = r & (TT-1);
    const long tr = idx[r];
    const float* te = tok + tr*CDIM;
    const float* pe = pos + (long)t*CDIM;
    float* xo = x + (long)r*CDIM;
    for (int c = threadIdx.x; c < CDIM; c += blockDim.x)
        xo[c] = te[c] + pe[c];
}

// One wave per row; 4 rows per block. addto: out[c] += ln(in[c]) else out = ln(in)
__global__ __launch_bounds__(256) void ln_kernel(
    const float* __restrict__ in, const float* __restrict__ g,
    const float* __restrict__ bb, float* __restrict__ out, int addto)
{
    const int wave = threadIdx.x >> 6;
    const int lane = threadIdx.x & 63;
    const long r = (long)blockIdx.x*4 + wave;
    const float* xr = in + r*CDIM;
    float vals[8];
    float s = 0.f;
    #pragma unroll
    for (int i = 0; i < 8; i++) { vals[i] = xr[lane + i*64]; s += vals[i]; }
    #pragma unroll
    for (int o = 32; o >= 1; o >>= 1) s += __shfl_xor(s, o);
    const float mean = s * (1.f/CDIM);
    float vs = 0.f;
    #pragma unroll
    for (int i = 0; i < 8; i++) { float d = vals[i]-mean; vs += d*d; }
    #pragma unroll
    for (int o = 32; o >= 1; o >>= 1) vs += __shfl_xor(vs, o);
    const float rstd = rsqrtf(vs*(1.f/CDIM) + 1e-5f);
    float* orow = out + r*CDIM;
    #pragma unroll
    for (int i = 0; i < 8; i++) {
        int c = lane + i*64;
        float nv = (vals[i]-mean)*rstd*g[c] + bb[c];
        orow[c] = addto ? (orow[c] + nv) : nv;
    }
}

// Flash attention, f32, no 1/sqrt(hs) scale (per reference).
// grid (TT/4, NH, BB), block 256 = 4 waves; wave w handles row t0+w.
__global__ __launch_bounds__(256) void attn_kernel(
    const float* __restrict__ qg, const float* __restrict__ kg,
    const float* __restrict__ vg, float* __restrict__ att)   // att: [BB,TT,CDIM]
{
    __shared__ float Ks[64*65];
    __shared__ float Vs[64*64];
    __shared__ float qs[4][64];
    const int wave = threadIdx.x >> 6, lane = threadIdx.x & 63;
    const int hh = blockIdx.y, b = blockIdx.z;
    const int t0 = blockIdx.x * 4;
    const int t = t0 + wave;
    const float* qb = qg + ((long)(b*NH + hh)*TT)*HS;
    const float* kb = kg + ((long)(b*NH + hh)*TT)*HS;
    const float* vb = vg + ((long)(b*NH + hh)*TT)*HS;
    qs[wave][lane] = qb[(long)t*HS + lane];
    float mrun = -INFINITY, lsum = 0.f, o = 0.f;
    const int send = t0 + 3;
    for (int s0 = 0; s0 <= send; s0 += 64) {
        __syncthreads();
        #pragma unroll
        for (int i = 0; i < 4; i++) {
            int e = threadIdx.x + i*256;     // 0..1023 float4 groups
            int rrow = e >> 4, c4 = (e & 15) << 2;
            float4 kv = *(const float4*)(kb + (long)(s0+rrow)*HS + c4);
            Ks[rrow*65 + c4+0] = kv.x; Ks[rrow*65 + c4+1] = kv.y;
            Ks[rrow*65 + c4+2] = kv.z; Ks[rrow*65 + c4+3] = kv.w;
            *(float4*)&Vs[rrow*64 + c4] = *(const float4*)(vb + (long)(s0+rrow)*HS + c4);
        }
        __syncthreads();
        float score = 0.f;
        #pragma unroll 16
        for (int d = 0; d < 64; d++)
            score += qs[wave][d] * Ks[lane*65 + d];
        const int s = s0 + lane;
        score = (s <= t) ? score : -INFINITY;
        float cmax = score;
        #pragma unroll
        for (int off = 32; off >= 1; off >>= 1) cmax = fmaxf(cmax, __shfl_xor(cmax, off));
        const float mnew = fmaxf(mrun, cmax);
        const float scale = __expf(mrun - mnew);   // first chunk: exp(-inf - finite) = 0
        const float p = __expf(score - mnew);      // masked: exp(-inf) = 0
        float psum = p;
        #pragma unroll
        for (int off = 32; off >= 1; off >>= 1) psum += __shfl_xor(psum, off);
        lsum = lsum*scale + psum;
        o *= scale;
        #pragma unroll 8
        for (int j = 0; j < 64; j++) {
            float pj = __shfl(p, j);
            o += pj * Vs[j*64 + lane];
        }
        mrun = mnew;
    }
    att[((long)b*TT + t)*CDIM + hh*HS + lane] = o / lsum;
}

extern "C" void kernel_launch(void* const* d_in, const int* in_sizes, int n_in,
                              void* d_out, int out_size, void* d_ws, size_t ws_size,
                              hipStream_t stream)
{
    const int*   idx   = (const int*)  d_in[0];
    const float* tok   = (const float*)d_in[1];
    const float* pos   = (const float*)d_in[2];
    const float* ln1g  = (const float*)d_in[3];
    const float* ln1b  = (const float*)d_in[4];
    const float* wq    = (const float*)d_in[5];
    const float* wk    = (const float*)d_in[6];
    const float* wv    = (const float*)d_in[7];
    const float* projw = (const float*)d_in[8];
    const float* projb = (const float*)d_in[9];
    const float* ln2g  = (const float*)d_in[10];
    const float* ln2b  = (const float*)d_in[11];
    const float* ffw1  = (const float*)d_in[12];
    const float* ffb1  = (const float*)d_in[13];
    const float* ffw2  = (const float*)d_in[14];
    const float* ffb2  = (const float*)d_in[15];
    const float* flng  = (const float*)d_in[16];
    const float* flnb  = (const float*)d_in[17];
    const float* lmw   = (const float*)d_in[18];
    const float* lmb   = (const float*)d_in[19];
    float* out = (float*)d_out;

    // workspace layout (f32): needs ~92.3 MB
    float* x   = (float*)d_ws;
    float* h   = x   + (size_t)MROWS*CDIM;
    float* q   = h   + (size_t)MROWS*CDIM;
    float* k   = q   + (size_t)MROWS*CDIM;   // B*H*T*HS == MROWS*CDIM
    float* v   = k   + (size_t)MROWS*CDIM;
    float* att = v   + (size_t)MROWS*CDIM;
    float* f1  = att + (size_t)MROWS*CDIM;
    float* ff  = f1  + (size_t)MROWS*4*CDIM;

    embed_kernel<<<MROWS, 256, 0, stream>>>(idx, tok, pos, x);

    for (int l = 0; l < NLAYER; l++) {
        ln_kernel<<<MROWS/4, 256, 0, stream>>>(x, ln1g + l*CDIM, ln1b + l*CDIM, h, 0);

        gemm_qkv_kernel<<<dim3(TT/BM, NH, 6), 256, 0, stream>>>(
            h, wq + (size_t)l*NH*CDIM*HS, wk + (size_t)l*NH*CDIM*HS,
            wv + (size_t)l*NH*CDIM*HS, q, k, v);

        attn_kernel<<<dim3(TT/4, NH, BB), 256, 0, stream>>>(q, k, v, att);

        // x = x + att @ proj_w^T + proj_b   (B transposed in memory)
        gemm_kernel<<<dim3(CDIM/BN, MROWS/BM), 256, 0, stream>>>(
            att, CDIM, projw + (size_t)l*CDIM*CDIM, CDIM, 1,
            projb + l*CDIM, x, CDIM, CDIM, 1|4);

        ln_kernel<<<MROWS/4, 256, 0, stream>>>(x, ln2g + l*CDIM, ln2b + l*CDIM, h, 0);

        // f1 = relu(h @ ff_w1 + b1)
        gemm_kernel<<<dim3(4*CDIM/BN, MROWS/BM), 256, 0, stream>>>(
            h, CDIM, ffw1 + (size_t)l*CDIM*4*CDIM, 4*CDIM, 0,
            ffb1 + (size_t)l*4*CDIM, f1, 4*CDIM, CDIM, 1|2);

        // ff = f1 @ ff_w2 + b2
        gemm_kernel<<<dim3(CDIM/BN, MROWS/BM), 256, 0, stream>>>(
            f1, 4*CDIM, ffw2 + (size_t)l*4*CDIM*CDIM, CDIM, 0,
            ffb2 + l*CDIM, ff, CDIM, 4*CDIM, 1);

        // x = x + LN(ff)
        ln_kernel<<<MROWS/4, 256, 0, stream>>>(ff, flng + l*CDIM, flnb + l*CDIM, x, 1);
    }

    // logits = x @ lm_w + lm_b
    gemm_kernel<<<dim3(VOCAB/BN, MROWS/BM), 256, 0, stream>>>(
        x, CDIM, lmw, VOCAB, 0, lmb, out, VOCAB, CDIM, 1);
}

// Round 3
// 4327.695 us; speedup vs baseline: 1.7786x; 1.7786x over previous
//
#include <hip/hip_runtime.h>
#include <math.h>

// Problem constants
#define NLAYER 4
#define NH     8
#define CDIM   512
#define HS     64
#define VOCAB  32000
#define BB     2
#define TT     2048
#define MROWS  (BB*TT)     // 4096
#define QKVW   (3*CDIM)    // 1536

typedef __attribute__((ext_vector_type(8))) short bf16x8;
typedef __attribute__((ext_vector_type(4))) float f32x4;

__device__ __forceinline__ unsigned short f2bf(float f) {
    unsigned int u = __float_as_uint(f);
    u += 0x7FFF + ((u >> 16) & 1);   // RNE
    return (unsigned short)(u >> 16);
}

#define GLOAD16(g, l) __builtin_amdgcn_global_load_lds( \
    (const __attribute__((address_space(1))) void*)(g), \
    (__attribute__((address_space(3))) void*)(l), 16, 0, 0)

// ---------------------------------------------------------------------------
// bf16 MFMA GEMM, m97 structure: 128x128 tile, BK=64, 4 waves, 16x16x32 MFMA.
// C[M,N] = A[M,K] @ Bt[N,K]^T. flags: 1=bias, 2=relu, 4=residual-add (f32).
// ---------------------------------------------------------------------------
template<int FLAGS, bool OUTBF>
__global__ __launch_bounds__(256) void mfma_gemm(
    const unsigned short* __restrict__ A, int lda,
    const unsigned short* __restrict__ Bt, int ldb,
    const float* __restrict__ bias,
    void* __restrict__ Cout, int ldc,
    const float* __restrict__ resid,
    int K)
{
    __shared__ unsigned short As[128*64];
    __shared__ unsigned short Bs[128*64];
    const int tid = threadIdx.x;
    const int w = tid >> 6, l = tid & 63;
    const int wr = w >> 1, wc = w & 1;           // wave -> 64x64 quadrant
    const long m0 = (long)blockIdx.y * 128;
    const long n0 = (long)blockIdx.x * 128;
    const int srow = l >> 3;                      // staging: row within 8-row segment
    const int scol = (l & 7) << 3;                // staging: k offset (8 bf16 = 16B)
    const unsigned short* Ab = A + m0*lda;
    const unsigned short* Bb = Bt + n0*ldb;
    const int fr = l & 15;                        // fragment row (m or n)
    const int fk = (l >> 4) << 3;                 // fragment k offset

    f32x4 acc[4][4];
    #pragma unroll
    for (int m = 0; m < 4; m++)
        #pragma unroll
        for (int n = 0; n < 4; n++) acc[m][n] = (f32x4)0.0f;

    for (int k0 = 0; k0 < K; k0 += 64) {
        __syncthreads();
        #pragma unroll
        for (int i = 0; i < 4; i++) {
            int seg = w*4 + i;                    // 16 segments of 8 rows
            GLOAD16(Ab + (long)(seg*8 + srow)*lda + k0 + scol, As + seg*512);
            GLOAD16(Bb + (long)(seg*8 + srow)*ldb + k0 + scol, Bs + seg*512);
        }
        __syncthreads();
        #pragma unroll
        for (int kk = 0; kk < 2; kk++) {
            bf16x8 af[4], bf[4];
            #pragma unroll
            for (int m = 0; m < 4; m++)
                af[m] = *(const bf16x8*)&As[(wr*64 + m*16 + fr)*64 + kk*32 + fk];
            #pragma unroll
            for (int n = 0; n < 4; n++)
                bf[n] = *(const bf16x8*)&Bs[(wc*64 + n*16 + fr)*64 + kk*32 + fk];
            #pragma unroll
            for (int m = 0; m < 4; m++)
                #pragma unroll
                for (int n = 0; n < 4; n++)
                    acc[m][n] = __builtin_amdgcn_mfma_f32_16x16x32_bf16(
                        af[m], bf[n], acc[m][n], 0, 0, 0);
        }
    }

    // epilogue: C/D layout col=lane&15, row=(lane>>4)*4+reg   [m89-verified]
    const int rg = (l >> 4) << 2;
    #pragma unroll
    for (int n = 0; n < 4; n++) {
        long gn = n0 + wc*64 + n*16 + fr;
        float bv = (FLAGS & 1) ? bias[gn] : 0.f;
        #pragma unroll
        for (int m = 0; m < 4; m++) {
            #pragma unroll
            for (int r = 0; r < 4; r++) {
                long gm = m0 + wr*64 + m*16 + rg + r;
                float val = acc[m][n][r] + bv;
                if (FLAGS & 2) val = fmaxf(val, 0.f);
                if (FLAGS & 4) val += resid[gm*ldc + gn];
                if (OUTBF) ((unsigned short*)Cout)[gm*ldc + gn] = f2bf(val);
                else       ((float*)Cout)[gm*ldc + gn] = val;
            }
        }
    }
}

// ---------------------------------------------------------------------------
// Weight prep: f32 [R][Cn] -> bf16 [Cn][R], batched via grid.z
// ---------------------------------------------------------------------------
__global__ __launch_bounds__(256) void transpose_cast(
    const float* __restrict__ in, unsigned short* __restrict__ out,
    int R, int Cn, long in_z1, long in_z2, long out_z1, long out_z2, int z2n)
{
    const int z = blockIdx.z;
    const int z1 = z / z2n, z2 = z % z2n;
    const float* ip = in + (long)z1*in_z1 + (long)z2*in_z2;
    unsigned short* op = out + (long)z1*out_z1 + (long)z2*out_z2;
    __shared__ float tile[32][33];
    const int tx = threadIdx.x & 31, ty = threadIdx.x >> 5;  // 32 x 8
    const long r0 = (long)blockIdx.y*32, c0 = (long)blockIdx.x*32;
    #pragma unroll
    for (int i = 0; i < 4; i++)
        tile[ty + i*8][tx] = ip[(r0 + ty + i*8)*Cn + c0 + tx];
    __syncthreads();
    #pragma unroll
    for (int i = 0; i < 4; i++)
        op[(c0 + ty + i*8)*R + r0 + tx] = f2bf(tile[tx][ty + i*8]);
}

__global__ __launch_bounds__(256) void cast_kernel(
    const float* __restrict__ in, unsigned short* __restrict__ out, long n)
{
    long i = ((long)blockIdx.x*256 + threadIdx.x) * 4;
    if (i >= n) return;
    float4 v = *(const float4*)(in + i);
    ushort4 u = make_ushort4(f2bf(v.x), f2bf(v.y), f2bf(v.z), f2bf(v.w));
    *(ushort4*)(out + i) = u;
}

// ---------------------------------------------------------------------------
__global__ void embed_kernel(const int* __restrict__ idx,
                             const float* __restrict__ tok,
                             const float* __restrict__ pos,
                             float* __restrict__ x)
{
    const int r = blockIdx.x;
    const int t = r & (TT-1);
    const long tr = idx[r];
    const float* te = tok + tr*CDIM;
    const float* pe = pos + (long)t*CDIM;
    float* xo = x + (long)r*CDIM;
    for (int c = threadIdx.x; c < CDIM; c += blockDim.x)
        xo[c] = te[c] + pe[c];
}

// MODE 1: out bf16 = LN(in).  MODE 2: out f32 += LN(in).
template<int MODE>
__global__ __launch_bounds__(256) void ln_kernel(
    const float* __restrict__ in, const float* __restrict__ g,
    const float* __restrict__ bb, void* __restrict__ outp)
{
    const int wave = threadIdx.x >> 6;
    const int lane = threadIdx.x & 63;
    const long r = (long)blockIdx.x*4 + wave;
    const float* xr = in + r*CDIM;
    float vals[8];
    float s = 0.f;
    #pragma unroll
    for (int i = 0; i < 8; i++) { vals[i] = xr[lane + i*64]; s += vals[i]; }
    #pragma unroll
    for (int o = 32; o >= 1; o >>= 1) s += __shfl_xor(s, o);
    const float mean = s * (1.f/CDIM);
    float vs = 0.f;
    #pragma unroll
    for (int i = 0; i < 8; i++) { float d = vals[i]-mean; vs += d*d; }
    #pragma unroll
    for (int o = 32; o >= 1; o >>= 1) vs += __shfl_xor(vs, o);
    const float rstd = rsqrtf(vs*(1.f/CDIM) + 1e-5f);
    #pragma unroll
    for (int i = 0; i < 8; i++) {
        int c = lane + i*64;
        float nv = (vals[i]-mean)*rstd*g[c] + bb[c];
        if (MODE == 1) ((unsigned short*)outp)[r*CDIM + c] = f2bf(nv);
        else           ((float*)outp)[r*CDIM + c] += nv;
    }
}

// ---------------------------------------------------------------------------
// Flash attention, f32, no 1/sqrt(hs) scale. qkv layout [B*T][3C] f32.
// grid (TT/4, NH, BB), 4 waves; wave w handles row t0+w. Output att bf16 [B,T,C].
// ---------------------------------------------------------------------------
__global__ __launch_bounds__(256) void attn_kernel(
    const float* __restrict__ qkv, unsigned short* __restrict__ att)
{
    __shared__ float Ks[64*65];
    __shared__ float Vs[64*64];
    __shared__ float qs[4][64];
    const int wave = threadIdx.x >> 6, lane = threadIdx.x & 63;
    const int hh = blockIdx.y, b = blockIdx.z;
    const int t0 = blockIdx.x * 4;
    const int t = t0 + wave;
    const float* base = qkv + (long)b*TT*QKVW;
    const float* qb = base + hh*HS;              // q cols [h*64..]
    const float* kb = base + CDIM   + hh*HS;     // k cols
    const float* vb = base + 2*CDIM + hh*HS;     // v cols
    qs[wave][lane] = qb[(long)t*QKVW + lane];
    float mrun = -INFINITY, lsum = 0.f, o = 0.f;
    const int send = t0 + 3;
    for (int s0 = 0; s0 <= send; s0 += 64) {
        __syncthreads();
        #pragma unroll
        for (int i = 0; i < 4; i++) {
            int e = threadIdx.x + i*256;
            int rrow = e >> 4, c4 = (e & 15) << 2;
            float4 kv = *(const float4*)(kb + (long)(s0+rrow)*QKVW + c4);
            Ks[rrow*65 + c4+0] = kv.x; Ks[rrow*65 + c4+1] = kv.y;
            Ks[rrow*65 + c4+2] = kv.z; Ks[rrow*65 + c4+3] = kv.w;
            *(float4*)&Vs[rrow*64 + c4] = *(const float4*)(vb + (long)(s0+rrow)*QKVW + c4);
        }
        __syncthreads();
        float score = 0.f;
        #pragma unroll 16
        for (int d = 0; d < 64; d++)
            score += qs[wave][d] * Ks[lane*65 + d];
        const int s = s0 + lane;
        score = (s <= t) ? score : -INFINITY;
        float cmax = score;
        #pragma unroll
        for (int off = 32; off >= 1; off >>= 1) cmax = fmaxf(cmax, __shfl_xor(cmax, off));
        const float mnew = fmaxf(mrun, cmax);
        const float scale = __expf(mrun - mnew);
        const float p = __expf(score - mnew);
        float psum = p;
        #pragma unroll
        for (int off = 32; off >= 1; off >>= 1) psum += __shfl_xor(psum, off);
        lsum = lsum*scale + psum;
        o *= scale;
        #pragma unroll 8
        for (int j = 0; j < 64; j++) {
            float pj = __shfl(p, j);
            o += pj * Vs[j*64 + lane];
        }
        mrun = mnew;
    }
    att[((long)b*TT + t)*CDIM + hh*HS + lane] = f2bf(o / lsum);
}

// ---------------------------------------------------------------------------
extern "C" void kernel_launch(void* const* d_in, const int* in_sizes, int n_in,
                              void* d_out, int out_size, void* d_ws, size_t ws_size,
                              hipStream_t stream)
{
    const int*   idx   = (const int*)  d_in[0];
    const float* tok   = (const float*)d_in[1];
    const float* pos   = (const float*)d_in[2];
    const float* ln1g  = (const float*)d_in[3];
    const float* ln1b  = (const float*)d_in[4];
    const float* wq    = (const float*)d_in[5];
    const float* wk    = (const float*)d_in[6];
    const float* wv    = (const float*)d_in[7];
    const float* projw = (const float*)d_in[8];
    const float* projb = (const float*)d_in[9];
    const float* ln2g  = (const float*)d_in[10];
    const float* ln2b  = (const float*)d_in[11];
    const float* ffw1  = (const float*)d_in[12];
    const float* ffb1  = (const float*)d_in[13];
    const float* ffw2  = (const float*)d_in[14];
    const float* ffb2  = (const float*)d_in[15];
    const float* flng  = (const float*)d_in[16];
    const float* flnb  = (const float*)d_in[17];
    const float* lmw   = (const float*)d_in[18];
    const float* lmb   = (const float*)d_in[19];
    float* out = (float*)d_out;

    // ---- workspace layout (~78 MB) ----
    char* wp = (char*)d_ws;
    float* x  = (float*)wp;           wp += (size_t)MROWS*CDIM*4;
    float* ff = (float*)wp;           wp += (size_t)MROWS*CDIM*4;
    unsigned short* h     = (unsigned short*)wp; wp += (size_t)MROWS*CDIM*2;
    unsigned short* lmt   = (unsigned short*)wp; wp += (size_t)VOCAB*CDIM*2;
    unsigned short* ff1t  = (unsigned short*)wp; wp += (size_t)NLAYER*4*CDIM*CDIM*2;
    unsigned short* ff2t  = (unsigned short*)wp; wp += (size_t)NLAYER*4*CDIM*CDIM*2;
    unsigned short* qkvt  = (unsigned short*)wp; wp += (size_t)NLAYER*QKVW*CDIM*2;
    unsigned short* projc = (unsigned short*)wp; wp += (size_t)NLAYER*CDIM*CDIM*2;

    // ---- scratch in d_out (dead before LM-head GEMM fully overwrites it) ----
    float* qkv = out;                                              // [MROWS][1536] f32
    unsigned short* f1  = (unsigned short*)(out + (size_t)MROWS*QKVW);  // [MROWS][2048] bf16
    unsigned short* att = f1 + (size_t)MROWS*4*CDIM;                    // [MROWS][512] bf16

    // ---- weight prep (bf16, [N][K] panels) ----
    // lm_w [512][32000] -> lmt [32000][512]
    transpose_cast<<<dim3(VOCAB/32, CDIM/32, 1), 256, 0, stream>>>(
        lmw, lmt, CDIM, VOCAB, 0, 0, 0, 0, 1);
    // ff_w1 [L][512][2048] -> ff1t [L][2048][512]
    transpose_cast<<<dim3(4*CDIM/32, CDIM/32, NLAYER), 256, 0, stream>>>(
        ffw1, ff1t, CDIM, 4*CDIM, (long)CDIM*4*CDIM, 0, (long)4*CDIM*CDIM, 0, 1);
    // ff_w2 [L][2048][512] -> ff2t [L][512][2048]
    transpose_cast<<<dim3(CDIM/32, 4*CDIM/32, NLAYER), 256, 0, stream>>>(
        ffw2, ff2t, 4*CDIM, CDIM, (long)4*CDIM*CDIM, 0, (long)CDIM*4*CDIM, 0, 1);
    // wq/wk/wv [L][H][512][64] -> qkvt rows: which*512 + h*64 + d, cols: c
    // which-block element offset = 512 rows * 512 cols = CDIM*CDIM  (round-2 bug: was CDIM)
    {
        const size_t QBLK = (size_t)CDIM * CDIM;   // 262144 elements
        transpose_cast<<<dim3(HS/32, CDIM/32, NLAYER*NH), 256, 0, stream>>>(
            wq, qkvt,            CDIM, HS,
            (long)NH*CDIM*HS, (long)CDIM*HS, (long)QKVW*CDIM, (long)HS*CDIM, NH);
        transpose_cast<<<dim3(HS/32, CDIM/32, NLAYER*NH), 256, 0, stream>>>(
            wk, qkvt + QBLK,     CDIM, HS,
            (long)NH*CDIM*HS, (long)CDIM*HS, (long)QKVW*CDIM, (long)HS*CDIM, NH);
        transpose_cast<<<dim3(HS/32, CDIM/32, NLAYER*NH), 256, 0, stream>>>(
            wv, qkvt + 2*QBLK,   CDIM, HS,
            (long)NH*CDIM*HS, (long)CDIM*HS, (long)QKVW*CDIM, (long)HS*CDIM, NH);
    }
    // proj_w [L][512][512] used as W^T -> plain cast (Bt[n][k] = proj_w[n][k])
    cast_kernel<<<(NLAYER*CDIM*CDIM/4 + 255)/256, 256, 0, stream>>>(
        projw, projc, (long)NLAYER*CDIM*CDIM);

    embed_kernel<<<MROWS, 256, 0, stream>>>(idx, tok, pos, x);

    for (int l = 0; l < NLAYER; l++) {
        const unsigned short* qkvt_l = qkvt + (size_t)l*QKVW*CDIM;
        const unsigned short* projc_l = projc + (size_t)l*CDIM*CDIM;
        const unsigned short* ff1t_l = ff1t + (size_t)l*4*CDIM*CDIM;
        const unsigned short* ff2t_l = ff2t + (size_t)l*4*CDIM*CDIM;

        ln_kernel<1><<<MROWS/4, 256, 0, stream>>>(x, ln1g + l*CDIM, ln1b + l*CDIM, h);

        mfma_gemm<0,false><<<dim3(QKVW/128, MROWS/128), 256, 0, stream>>>(
            h, CDIM, qkvt_l, CDIM, nullptr, qkv, QKVW, nullptr, CDIM);

        attn_kernel<<<dim3(TT/4, NH, BB), 256, 0, stream>>>(qkv, att);

        mfma_gemm<5,false><<<dim3(CDIM/128, MROWS/128), 256, 0, stream>>>(
            att, CDIM, projc_l, CDIM, projb + l*CDIM, x, CDIM, x, CDIM);

        ln_kernel<1><<<MROWS/4, 256, 0, stream>>>(x, ln2g + l*CDIM, ln2b + l*CDIM, h);

        mfma_gemm<3,true><<<dim3(4*CDIM/128, MROWS/128), 256, 0, stream>>>(
            h, CDIM, ff1t_l, CDIM, ffb1 + (size_t)l*4*CDIM, f1, 4*CDIM, nullptr, CDIM);

        mfma_gemm<1,false><<<dim3(CDIM/128, MROWS/128), 256, 0, stream>>>(
            f1, 4*CDIM, ff2t_l, 4*CDIM, ffb2 + l*CDIM, ff, CDIM, nullptr, 4*CDIM);

        ln_kernel<2><<<MROWS/4, 256, 0, stream>>>(ff, flng + l*CDIM, flnb + l*CDIM, x);
    }

    // LM head: out = x @ lm_w + lm_b
    cast_kernel<<<(MROWS*CDIM/4 + 255)/256, 256, 0, stream>>>(x, h, (long)MROWS*CDIM);
    mfma_gemm<1,false><<<dim3(VOCAB/128, MROWS/128), 256, 0, stream>>>(
        h, CDIM, lmt, CDIM, lmb, out, VOCAB, nullptr, CDIM);
}

// Round 4
// 1132.249 us; speedup vs baseline: 6.7981x; 3.8222x over previous
//
#include <hip/hip_runtime.h>
#include <math.h>

// Problem constants
#define NLAYER 4
#define NH     8
#define CDIM   512
#define HS     64
#define VOCAB  32000
#define BB     2
#define TT     2048
#define MROWS  (BB*TT)     // 4096
#define QKVW   (3*CDIM)    // 1536

typedef __attribute__((ext_vector_type(8))) short bf16x8;
typedef __attribute__((ext_vector_type(4))) float f32x4;

__device__ __forceinline__ unsigned short f2bf(float f) {
    unsigned int u = __float_as_uint(f);
    u += 0x7FFF + ((u >> 16) & 1);   // RNE
    return (unsigned short)(u >> 16);
}

#define GLOAD16(g, l) __builtin_amdgcn_global_load_lds( \
    (const __attribute__((address_space(1))) void*)(g), \
    (__attribute__((address_space(3))) void*)(l), 16, 0, 0)

// ---------------------------------------------------------------------------
// bf16 MFMA GEMM, m97 structure: 128x128 tile, BK=64, 4 waves, 16x16x32 MFMA.
// C[M,N] = A[M,K] @ Bt[N,K]^T. flags: 1=bias, 2=relu, 4=residual-add (f32).
// ---------------------------------------------------------------------------
template<int FLAGS, bool OUTBF>
__global__ __launch_bounds__(256) void mfma_gemm(
    const unsigned short* __restrict__ A, int lda,
    const unsigned short* __restrict__ Bt, int ldb,
    const float* __restrict__ bias,
    void* __restrict__ Cout, int ldc,
    const float* __restrict__ resid,
    int K)
{
    __shared__ unsigned short As[128*64];
    __shared__ unsigned short Bs[128*64];
    const int tid = threadIdx.x;
    const int w = tid >> 6, l = tid & 63;
    const int wr = w >> 1, wc = w & 1;
    const long m0 = (long)blockIdx.y * 128;
    const long n0 = (long)blockIdx.x * 128;
    const int srow = l >> 3;
    const int scol = (l & 7) << 3;
    const unsigned short* Ab = A + m0*lda;
    const unsigned short* Bb = Bt + n0*ldb;
    const int fr = l & 15;
    const int fk = (l >> 4) << 3;

    f32x4 acc[4][4];
    #pragma unroll
    for (int m = 0; m < 4; m++)
        #pragma unroll
        for (int n = 0; n < 4; n++) acc[m][n] = (f32x4)0.0f;

    for (int k0 = 0; k0 < K; k0 += 64) {
        __syncthreads();
        #pragma unroll
        for (int i = 0; i < 4; i++) {
            int seg = w*4 + i;
            GLOAD16(Ab + (long)(seg*8 + srow)*lda + k0 + scol, As + seg*512);
            GLOAD16(Bb + (long)(seg*8 + srow)*ldb + k0 + scol, Bs + seg*512);
        }
        __syncthreads();
        #pragma unroll
        for (int kk = 0; kk < 2; kk++) {
            bf16x8 af[4], bf[4];
            #pragma unroll
            for (int m = 0; m < 4; m++)
                af[m] = *(const bf16x8*)&As[(wr*64 + m*16 + fr)*64 + kk*32 + fk];
            #pragma unroll
            for (int n = 0; n < 4; n++)
                bf[n] = *(const bf16x8*)&Bs[(wc*64 + n*16 + fr)*64 + kk*32 + fk];
            #pragma unroll
            for (int m = 0; m < 4; m++)
                #pragma unroll
                for (int n = 0; n < 4; n++)
                    acc[m][n] = __builtin_amdgcn_mfma_f32_16x16x32_bf16(
                        af[m], bf[n], acc[m][n], 0, 0, 0);
        }
    }

    const int rg = (l >> 4) << 2;
    #pragma unroll
    for (int n = 0; n < 4; n++) {
        long gn = n0 + wc*64 + n*16 + fr;
        float bv = (FLAGS & 1) ? bias[gn] : 0.f;
        #pragma unroll
        for (int m = 0; m < 4; m++) {
            #pragma unroll
            for (int r = 0; r < 4; r++) {
                long gm = m0 + wr*64 + m*16 + rg + r;
                float val = acc[m][n][r] + bv;
                if (FLAGS & 2) val = fmaxf(val, 0.f);
                if (FLAGS & 4) val += resid[gm*ldc + gn];
                if (OUTBF) ((unsigned short*)Cout)[gm*ldc + gn] = f2bf(val);
                else       ((float*)Cout)[gm*ldc + gn] = val;
            }
        }
    }
}

// ---------------------------------------------------------------------------
// QKV GEMM: same core, scatter epilogue -> qh/kh [head][t][d], vt [head][d][t]
// A = h [4096][512], Bt = qkvt_l [1536][512]. grid (12, 32).
// ---------------------------------------------------------------------------
__global__ __launch_bounds__(256) void mfma_gemm_qkv(
    const unsigned short* __restrict__ A,
    const unsigned short* __restrict__ Bt,
    unsigned short* __restrict__ qh,
    unsigned short* __restrict__ kh,
    unsigned short* __restrict__ vt)
{
    __shared__ unsigned short As[128*64];
    __shared__ unsigned short Bs[128*64];
    const int tid = threadIdx.x;
    const int w = tid >> 6, l = tid & 63;
    const int wr = w >> 1, wc = w & 1;
    const long m0 = (long)blockIdx.y * 128;
    const long n0 = (long)blockIdx.x * 128;
    const int srow = l >> 3;
    const int scol = (l & 7) << 3;
    const unsigned short* Ab = A + m0*CDIM;
    const unsigned short* Bb = Bt + n0*CDIM;
    const int fr = l & 15;
    const int fk = (l >> 4) << 3;

    f32x4 acc[4][4];
    #pragma unroll
    for (int m = 0; m < 4; m++)
        #pragma unroll
        for (int n = 0; n < 4; n++) acc[m][n] = (f32x4)0.0f;

    for (int k0 = 0; k0 < CDIM; k0 += 64) {
        __syncthreads();
        #pragma unroll
        for (int i = 0; i < 4; i++) {
            int seg = w*4 + i;
            GLOAD16(Ab + (long)(seg*8 + srow)*CDIM + k0 + scol, As + seg*512);
            GLOAD16(Bb + (long)(seg*8 + srow)*CDIM + k0 + scol, Bs + seg*512);
        }
        __syncthreads();
        #pragma unroll
        for (int kk = 0; kk < 2; kk++) {
            bf16x8 af[4], bf[4];
            #pragma unroll
            for (int m = 0; m < 4; m++)
                af[m] = *(const bf16x8*)&As[(wr*64 + m*16 + fr)*64 + kk*32 + fk];
            #pragma unroll
            for (int n = 0; n < 4; n++)
                bf[n] = *(const bf16x8*)&Bs[(wc*64 + n*16 + fr)*64 + kk*32 + fk];
            #pragma unroll
            for (int m = 0; m < 4; m++)
                #pragma unroll
                for (int n = 0; n < 4; n++)
                    acc[m][n] = __builtin_amdgcn_mfma_f32_16x16x32_bf16(
                        af[m], bf[n], acc[m][n], 0, 0, 0);
        }
    }

    const int rg = (l >> 4) << 2;
    #pragma unroll
    for (int n = 0; n < 4; n++) {
        int gn = (int)(n0 + wc*64 + n*16 + fr);
        int which = gn >> 9, hh = (gn >> 6) & 7, d = gn & 63;
        #pragma unroll
        for (int m = 0; m < 4; m++) {
            #pragma unroll
            for (int r = 0; r < 4; r++) {
                int gm = (int)(m0 + wr*64 + m*16 + rg + r);
                int b = gm >> 11, t = gm & (TT-1);
                int head = b*NH + hh;
                unsigned short val = f2bf(acc[m][n][r]);
                if (which == 0)      qh[((long)head*TT + t)*HS + d] = val;
                else if (which == 1) kh[((long)head*TT + t)*HS + d] = val;
                else                 vt[((long)head*HS + d)*TT + t] = val;
            }
        }
    }
}

// ---------------------------------------------------------------------------
// MFMA flash attention. grid (TT/128, BB*NH). 4 waves x 32 q-rows.
// qh/kh: [head][t][64] bf16; vt: [head][64][t] bf16. No 1/sqrt(hs) scale.
// K/V LDS XOR-swizzled (write side via pre-swizzled global col, read side u^row&7).
// ---------------------------------------------------------------------------
__global__ __launch_bounds__(256) void attn_mfma(
    const unsigned short* __restrict__ qh,
    const unsigned short* __restrict__ kh,
    const unsigned short* __restrict__ vt,
    unsigned short* __restrict__ att)
{
    __shared__ unsigned short Ks[2][64*64];
    __shared__ unsigned short Vts[2][64*64];
    __shared__ unsigned short Ps[4][32*72];
    const int tid = threadIdx.x;
    const int w = tid >> 6, l = tid & 63;
    const int fr = l & 15, g = l >> 4;
    const int head = blockIdx.y;
    const int b = head >> 3, hh = head & 7;
    const int qt0 = blockIdx.x * 128;
    const int qw = qt0 + w*32;
    const unsigned short* Qb = qh + (long)head*TT*HS;
    const unsigned short* Kb = kh + (long)head*TT*HS;
    const unsigned short* Vb = vt + (long)head*HS*TT;

    // Q fragments (A-layout): lane holds Q[row fr][k-slice ks*32+g*8]
    bf16x8 aq[2][2];
    #pragma unroll
    for (int mt = 0; mt < 2; mt++)
        #pragma unroll
        for (int ks = 0; ks < 2; ks++)
            aq[mt][ks] = *(const bf16x8*)&Qb[(long)(qw + mt*16 + fr)*HS + ks*32 + g*8];

    f32x4 acc_o[2][4];
    float mrun[2][4], lsum[2][4];
    #pragma unroll
    for (int mt = 0; mt < 2; mt++) {
        #pragma unroll
        for (int r = 0; r < 4; r++) { mrun[mt][r] = -INFINITY; lsum[mt][r] = 0.f; }
        #pragma unroll
        for (int n = 0; n < 4; n++) acc_o[mt][n] = (f32x4)0.0f;
    }

    const int nch = 2*blockIdx.x + 2;
    const int srow = l >> 3;                          // 0..7 within 8-row seg
    const int scol = ((l & 7) ^ (srow & 7)) << 3;     // inverse-swizzled global col (elems)

    auto stage = [&](int c, int buf) {
        int s0_ = c*64;
        #pragma unroll
        for (int i = 0; i < 2; i++) {
            int rb = i*32 + w*8;
            GLOAD16(Kb + (long)(s0_ + rb + srow)*HS + scol, &Ks[buf][rb*64]);
            GLOAD16(Vb + (long)(rb + srow)*TT + s0_ + scol, &Vts[buf][rb*64]);
        }
    };

    stage(0, 0);
    for (int c = 0; c < nch; c++) {
        const int s0 = c*64;
        const int buf = c & 1;
        __syncthreads();                  // drains vmcnt: buf[c] staged; prev buffer free
        if (c + 1 < nch) stage(c+1, (c+1)&1);
        if (s0 > qw + 31) continue;       // wave-uniform skip; staging already done

        // --- S = Q K^T (K read with swizzle) ---
        bf16x8 bk[4][2];
        #pragma unroll
        for (int n = 0; n < 4; n++)
            #pragma unroll
            for (int ks = 0; ks < 2; ks++) {
                int row = n*16 + fr;
                int u = (ks*4 + g) ^ (row & 7);
                bk[n][ks] = *(const bf16x8*)&Ks[buf][row*64 + u*8];
            }
        f32x4 sc[2][4];
        #pragma unroll
        for (int mt = 0; mt < 2; mt++)
            #pragma unroll
            for (int n = 0; n < 4; n++) sc[mt][n] = (f32x4)0.0f;
        #pragma unroll
        for (int ks = 0; ks < 2; ks++)
            #pragma unroll
            for (int mt = 0; mt < 2; mt++)
                #pragma unroll
                for (int n = 0; n < 4; n++)
                    sc[mt][n] = __builtin_amdgcn_mfma_f32_16x16x32_bf16(
                        aq[mt][ks], bk[n][ks], sc[mt][n], 0, 0, 0);

        // --- causal mask + online softmax (row = q: mt, reg r) ---
        #pragma unroll
        for (int mt = 0; mt < 2; mt++) {
            #pragma unroll
            for (int r = 0; r < 4; r++) {
                int q = qw + mt*16 + g*4 + r;
                float rmax = -INFINITY;
                #pragma unroll
                for (int n = 0; n < 4; n++) {
                    float v = sc[mt][n][r];
                    v = (s0 + n*16 + fr <= q) ? v : -INFINITY;
                    sc[mt][n][r] = v;
                    rmax = fmaxf(rmax, v);
                }
                #pragma unroll
                for (int off = 8; off >= 1; off >>= 1)
                    rmax = fmaxf(rmax, __shfl_xor(rmax, off));
                float mnew = fmaxf(mrun[mt][r], rmax);
                float scale = __expf(mrun[mt][r] - mnew);   // -inf -> 0; mnew finite post-chunk0
                float ps = 0.f;
                #pragma unroll
                for (int n = 0; n < 4; n++) {
                    float p = __expf(sc[mt][n][r] - mnew);
                    sc[mt][n][r] = p;
                    ps += p;
                }
                #pragma unroll
                for (int off = 8; off >= 1; off >>= 1)
                    ps += __shfl_xor(ps, off);
                lsum[mt][r] = lsum[mt][r]*scale + ps;
                mrun[mt][r] = mnew;
                #pragma unroll
                for (int n = 0; n < 4; n++) acc_o[mt][n][r] *= scale;
            }
        }

        // --- P -> LDS (C-layout -> A-layout transpose), padded rows (72) ---
        #pragma unroll
        for (int mt = 0; mt < 2; mt++)
            #pragma unroll
            for (int n = 0; n < 4; n++)
                #pragma unroll
                for (int r = 0; r < 4; r++)
                    Ps[w][(mt*16 + g*4 + r)*72 + n*16 + fr] = f2bf(sc[mt][n][r]);

        // --- O += P V  (Vt read with swizzle) ---
        bf16x8 ap[2][2], bv[4][2];
        #pragma unroll
        for (int mt = 0; mt < 2; mt++)
            #pragma unroll
            for (int ks = 0; ks < 2; ks++)
                ap[mt][ks] = *(const bf16x8*)&Ps[w][(mt*16 + fr)*72 + ks*32 + g*8];
        #pragma unroll
        for (int n = 0; n < 4; n++)
            #pragma unroll
            for (int ks = 0; ks < 2; ks++) {
                int row = n*16 + fr;
                int u = (ks*4 + g) ^ (row & 7);
                bv[n][ks] = *(const bf16x8*)&Vts[buf][row*64 + u*8];
            }
        #pragma unroll
        for (int ks = 0; ks < 2; ks++)
            #pragma unroll
            for (int mt = 0; mt < 2; mt++)
                #pragma unroll
                for (int n = 0; n < 4; n++)
                    acc_o[mt][n] = __builtin_amdgcn_mfma_f32_16x16x32_bf16(
                        ap[mt][ks], bv[n][ks], acc_o[mt][n], 0, 0, 0);
    }

    // output: att [B*T][C] bf16
    #pragma unroll
    for (int mt = 0; mt < 2; mt++)
        #pragma unroll
        for (int n = 0; n < 4; n++)
            #pragma unroll
            for (int r = 0; r < 4; r++) {
                int t = qw + mt*16 + g*4 + r;
                int d = n*16 + fr;
                att[((long)b*TT + t)*CDIM + hh*HS + d] =
                    f2bf(acc_o[mt][n][r] / lsum[mt][r]);
            }
}

// ---------------------------------------------------------------------------
// Weight prep: f32 [R][Cn] -> bf16 [Cn][R], batched via grid.z
// ---------------------------------------------------------------------------
__global__ __launch_bounds__(256) void transpose_cast(
    const float* __restrict__ in, unsigned short* __restrict__ out,
    int R, int Cn, long in_z1, long in_z2, long out_z1, long out_z2, int z2n)
{
    const int z = blockIdx.z;
    const int z1 = z / z2n, z2 = z % z2n;
    const float* ip = in + (long)z1*in_z1 + (long)z2*in_z2;
    unsigned short* op = out + (long)z1*out_z1 + (long)z2*out_z2;
    __shared__ float tile[32][33];
    const int tx = threadIdx.x & 31, ty = threadIdx.x >> 5;
    const long r0 = (long)blockIdx.y*32, c0 = (long)blockIdx.x*32;
    #pragma unroll
    for (int i = 0; i < 4; i++)
        tile[ty + i*8][tx] = ip[(r0 + ty + i*8)*Cn + c0 + tx];
    __syncthreads();
    #pragma unroll
    for (int i = 0; i < 4; i++)
        op[(c0 + ty + i*8)*R + r0 + tx] = f2bf(tile[tx][ty + i*8]);
}

__global__ __launch_bounds__(256) void cast_kernel(
    const float* __restrict__ in, unsigned short* __restrict__ out, long n)
{
    long i = ((long)blockIdx.x*256 + threadIdx.x) * 4;
    if (i >= n) return;
    float4 v = *(const float4*)(in + i);
    ushort4 u = make_ushort4(f2bf(v.x), f2bf(v.y), f2bf(v.z), f2bf(v.w));
    *(ushort4*)(out + i) = u;
}

// ---------------------------------------------------------------------------
__global__ void embed_kernel(const int* __restrict__ idx,
                             const float* __restrict__ tok,
                             const float* __restrict__ pos,
                             float* __restrict__ x)
{
    const int r = blockIdx.x;
    const int t = r & (TT-1);
    const long tr = idx[r];
    const float* te = tok + tr*CDIM;
    const float* pe = pos + (long)t*CDIM;
    float* xo = x + (long)r*CDIM;
    for (int c = threadIdx.x; c < CDIM; c += blockDim.x)
        xo[c] = te[c] + pe[c];
}

// MODE 1: out bf16 = LN(in).  MODE 2: out f32 += LN(in).
template<int MODE>
__global__ __launch_bounds__(256) void ln_kernel(
    const float* __restrict__ in, const float* __restrict__ g,
    const float* __restrict__ bb, void* __restrict__ outp)
{
    const int wave = threadIdx.x >> 6;
    const int lane = threadIdx.x & 63;
    const long r = (long)blockIdx.x*4 + wave;
    const float* xr = in + r*CDIM;
    float vals[8];
    float s = 0.f;
    #pragma unroll
    for (int i = 0; i < 8; i++) { vals[i] = xr[lane + i*64]; s += vals[i]; }
    #pragma unroll
    for (int o = 32; o >= 1; o >>= 1) s += __shfl_xor(s, o);
    const float mean = s * (1.f/CDIM);
    float vs = 0.f;
    #pragma unroll
    for (int i = 0; i < 8; i++) { float d = vals[i]-mean; vs += d*d; }
    #pragma unroll
    for (int o = 32; o >= 1; o >>= 1) vs += __shfl_xor(vs, o);
    const float rstd = rsqrtf(vs*(1.f/CDIM) + 1e-5f);
    #pragma unroll
    for (int i = 0; i < 8; i++) {
        int c = lane + i*64;
        float nv = (vals[i]-mean)*rstd*g[c] + bb[c];
        if (MODE == 1) ((unsigned short*)outp)[r*CDIM + c] = f2bf(nv);
        else           ((float*)outp)[r*CDIM + c] += nv;
    }
}

// ---------------------------------------------------------------------------
extern "C" void kernel_launch(void* const* d_in, const int* in_sizes, int n_in,
                              void* d_out, int out_size, void* d_ws, size_t ws_size,
                              hipStream_t stream)
{
    const int*   idx   = (const int*)  d_in[0];
    const float* tok   = (const float*)d_in[1];
    const float* pos   = (const float*)d_in[2];
    const float* ln1g  = (const float*)d_in[3];
    const float* ln1b  = (const float*)d_in[4];
    const float* wq    = (const float*)d_in[5];
    const float* wk    = (const float*)d_in[6];
    const float* wv    = (const float*)d_in[7];
    const float* projw = (const float*)d_in[8];
    const float* projb = (const float*)d_in[9];
    const float* ln2g  = (const float*)d_in[10];
    const float* ln2b  = (const float*)d_in[11];
    const float* ffw1  = (const float*)d_in[12];
    const float* ffb1  = (const float*)d_in[13];
    const float* ffw2  = (const float*)d_in[14];
    const float* ffb2  = (const float*)d_in[15];
    const float* flng  = (const float*)d_in[16];
    const float* flnb  = (const float*)d_in[17];
    const float* lmw   = (const float*)d_in[18];
    const float* lmb   = (const float*)d_in[19];
    float* out = (float*)d_out;

    // ---- workspace layout (~91.5 MB) ----
    char* wp = (char*)d_ws;
    float* x  = (float*)wp;           wp += (size_t)MROWS*CDIM*4;
    float* ff = (float*)wp;           wp += (size_t)MROWS*CDIM*4;
    unsigned short* h     = (unsigned short*)wp; wp += (size_t)MROWS*CDIM*2;
    unsigned short* lmt   = (unsigned short*)wp; wp += (size_t)VOCAB*CDIM*2;
    unsigned short* ff1t  = (unsigned short*)wp; wp += (size_t)NLAYER*4*CDIM*CDIM*2;
    unsigned short* ff2t  = (unsigned short*)wp; wp += (size_t)NLAYER*4*CDIM*CDIM*2;
    unsigned short* qkvt  = (unsigned short*)wp; wp += (size_t)NLAYER*QKVW*CDIM*2;
    unsigned short* projc = (unsigned short*)wp; wp += (size_t)NLAYER*CDIM*CDIM*2;
    unsigned short* qh    = (unsigned short*)wp; wp += (size_t)BB*NH*TT*HS*2;
    unsigned short* kh    = (unsigned short*)wp; wp += (size_t)BB*NH*TT*HS*2;
    unsigned short* vt    = (unsigned short*)wp; wp += (size_t)BB*NH*TT*HS*2;

    // ---- scratch in d_out (dead before LM-head GEMM fully overwrites it) ----
    unsigned short* f1  = (unsigned short*)d_out;          // [MROWS][2048] bf16
    unsigned short* att = f1 + (size_t)MROWS*4*CDIM;       // [MROWS][512] bf16

    // ---- weight prep (bf16, [N][K] panels) ----
    transpose_cast<<<dim3(VOCAB/32, CDIM/32, 1), 256, 0, stream>>>(
        lmw, lmt, CDIM, VOCAB, 0, 0, 0, 0, 1);
    transpose_cast<<<dim3(4*CDIM/32, CDIM/32, NLAYER), 256, 0, stream>>>(
        ffw1, ff1t, CDIM, 4*CDIM, (long)CDIM*4*CDIM, 0, (long)4*CDIM*CDIM, 0, 1);
    transpose_cast<<<dim3(CDIM/32, 4*CDIM/32, NLAYER), 256, 0, stream>>>(
        ffw2, ff2t, 4*CDIM, CDIM, (long)4*CDIM*CDIM, 0, (long)CDIM*4*CDIM, 0, 1);
    {
        const size_t QBLK = (size_t)CDIM * CDIM;   // 262144 elements
        transpose_cast<<<dim3(HS/32, CDIM/32, NLAYER*NH), 256, 0, stream>>>(
            wq, qkvt,            CDIM, HS,
            (long)NH*CDIM*HS, (long)CDIM*HS, (long)QKVW*CDIM, (long)HS*CDIM, NH);
        transpose_cast<<<dim3(HS/32, CDIM/32, NLAYER*NH), 256, 0, stream>>>(
            wk, qkvt + QBLK,     CDIM, HS,
            (long)NH*CDIM*HS, (long)CDIM*HS, (long)QKVW*CDIM, (long)HS*CDIM, NH);
        transpose_cast<<<dim3(HS/32, CDIM/32, NLAYER*NH), 256, 0, stream>>>(
            wv, qkvt + 2*QBLK,   CDIM, HS,
            (long)NH*CDIM*HS, (long)CDIM*HS, (long)QKVW*CDIM, (long)HS*CDIM, NH);
    }
    cast_kernel<<<(NLAYER*CDIM*CDIM/4 + 255)/256, 256, 0, stream>>>(
        projw, projc, (long)NLAYER*CDIM*CDIM);

    embed_kernel<<<MROWS, 256, 0, stream>>>(idx, tok, pos, x);

    for (int l = 0; l < NLAYER; l++) {
        const unsigned short* qkvt_l = qkvt + (size_t)l*QKVW*CDIM;
        const unsigned short* projc_l = projc + (size_t)l*CDIM*CDIM;
        const unsigned short* ff1t_l = ff1t + (size_t)l*4*CDIM*CDIM;
        const unsigned short* ff2t_l = ff2t + (size_t)l*4*CDIM*CDIM;

        ln_kernel<1><<<MROWS/4, 256, 0, stream>>>(x, ln1g + l*CDIM, ln1b + l*CDIM, h);

        mfma_gemm_qkv<<<dim3(QKVW/128, MROWS/128), 256, 0, stream>>>(
            h, qkvt_l, qh, kh, vt);

        attn_mfma<<<dim3(TT/128, BB*NH), 256, 0, stream>>>(qh, kh, vt, att);

        mfma_gemm<5,false><<<dim3(CDIM/128, MROWS/128), 256, 0, stream>>>(
            att, CDIM, projc_l, CDIM, projb + l*CDIM, x, CDIM, x, CDIM);

        ln_kernel<1><<<MROWS/4, 256, 0, stream>>>(x, ln2g + l*CDIM, ln2b + l*CDIM, h);

        mfma_gemm<3,true><<<dim3(4*CDIM/128, MROWS/128), 256, 0, stream>>>(
            h, CDIM, ff1t_l, CDIM, ffb1 + (size_t)l*4*CDIM, f1, 4*CDIM, nullptr, CDIM);

        mfma_gemm<1,false><<<dim3(CDIM/128, MROWS/128), 256, 0, stream>>>(
            f1, 4*CDIM, ff2t_l, 4*CDIM, ffb2 + l*CDIM, ff, CDIM, nullptr, 4*CDIM);

        ln_kernel<2><<<MROWS/4, 256, 0, stream>>>(ff, flng + l*CDIM, flnb + l*CDIM, x);
    }

    // LM head: out = x @ lm_w + lm_b
    cast_kernel<<<(MROWS*CDIM/4 + 255)/256, 256, 0, stream>>>(x, h, (long)MROWS*CDIM);
    mfma_gemm<1,false><<<dim3(VOCAB/128, MROWS/128), 256, 0, stream>>>(
        h, CDIM, lmt, CDIM, lmb, out, VOCAB, nullptr, CDIM);
}

// Round 5
// 1033.699 us; speedup vs baseline: 7.4462x; 1.0953x over previous
//
#include <hip/hip_runtime.h>
#include <math.h>

// Problem constants
#define NLAYER 4
#define NH     8
#define CDIM   512
#define HS     64
#define VOCAB  32000
#define BB     2
#define TT     2048
#define MROWS  (BB*TT)     // 4096
#define QKVW   (3*CDIM)    // 1536
#define NHEADS (BB*NH)     // 16

typedef __attribute__((ext_vector_type(8))) short bf16x8;
typedef __attribute__((ext_vector_type(4))) float f32x4;

__device__ __forceinline__ unsigned short f2bf(float f) {
    unsigned int u = __float_as_uint(f);
    u += 0x7FFF + ((u >> 16) & 1);   // RNE
    return (unsigned short)(u >> 16);
}

#define GLOAD16(g, l) __builtin_amdgcn_global_load_lds( \
    (const __attribute__((address_space(1))) void*)(g), \
    (__attribute__((address_space(3))) void*)(l), 16, 0, 0)

// ---------------------------------------------------------------------------
// bf16 MFMA GEMM, m97 structure: 128x128 tile, BK=64, 4 waves, 16x16x32 MFMA.
// C[M,N] = A[M,K] @ Bt[N,K]^T. flags: 1=bias, 2=relu, 4=residual-add (f32).
// ---------------------------------------------------------------------------
template<int FLAGS, bool OUTBF>
__global__ __launch_bounds__(256) void mfma_gemm(
    const unsigned short* __restrict__ A, int lda,
    const unsigned short* __restrict__ Bt, int ldb,
    const float* __restrict__ bias,
    void* __restrict__ Cout, int ldc,
    const float* __restrict__ resid,
    int K)
{
    __shared__ unsigned short As[128*64];
    __shared__ unsigned short Bs[128*64];
    const int tid = threadIdx.x;
    const int w = tid >> 6, l = tid & 63;
    const int wr = w >> 1, wc = w & 1;
    const long m0 = (long)blockIdx.y * 128;
    const long n0 = (long)blockIdx.x * 128;
    const int srow = l >> 3;
    const int scol = (l & 7) << 3;
    const unsigned short* Ab = A + m0*lda;
    const unsigned short* Bb = Bt + n0*ldb;
    const int fr = l & 15;
    const int fk = (l >> 4) << 3;

    f32x4 acc[4][4];
    #pragma unroll
    for (int m = 0; m < 4; m++)
        #pragma unroll
        for (int n = 0; n < 4; n++) acc[m][n] = (f32x4)0.0f;

    for (int k0 = 0; k0 < K; k0 += 64) {
        __syncthreads();
        #pragma unroll
        for (int i = 0; i < 4; i++) {
            int seg = w*4 + i;
            GLOAD16(Ab + (long)(seg*8 + srow)*lda + k0 + scol, As + seg*512);
            GLOAD16(Bb + (long)(seg*8 + srow)*ldb + k0 + scol, Bs + seg*512);
        }
        __syncthreads();
        #pragma unroll
        for (int kk = 0; kk < 2; kk++) {
            bf16x8 af[4], bf[4];
            #pragma unroll
            for (int m = 0; m < 4; m++)
                af[m] = *(const bf16x8*)&As[(wr*64 + m*16 + fr)*64 + kk*32 + fk];
            #pragma unroll
            for (int n = 0; n < 4; n++)
                bf[n] = *(const bf16x8*)&Bs[(wc*64 + n*16 + fr)*64 + kk*32 + fk];
            #pragma unroll
            for (int m = 0; m < 4; m++)
                #pragma unroll
                for (int n = 0; n < 4; n++)
                    acc[m][n] = __builtin_amdgcn_mfma_f32_16x16x32_bf16(
                        af[m], bf[n], acc[m][n], 0, 0, 0);
        }
    }

    const int rg = (l >> 4) << 2;
    #pragma unroll
    for (int n = 0; n < 4; n++) {
        long gn = n0 + wc*64 + n*16 + fr;
        float bv = (FLAGS & 1) ? bias[gn] : 0.f;
        #pragma unroll
        for (int m = 0; m < 4; m++) {
            #pragma unroll
            for (int r = 0; r < 4; r++) {
                long gm = m0 + wr*64 + m*16 + rg + r;
                float val = acc[m][n][r] + bv;
                if (FLAGS & 2) val = fmaxf(val, 0.f);
                if (FLAGS & 4) val += resid[gm*ldc + gn];
                if (OUTBF) ((unsigned short*)Cout)[gm*ldc + gn] = f2bf(val);
                else       ((float*)Cout)[gm*ldc + gn] = val;
            }
        }
    }
}

// ---------------------------------------------------------------------------
// QKV GEMM: same core, scatter epilogue -> qh/kh [head][t][d], vt [head][d][t]
// ---------------------------------------------------------------------------
__global__ __launch_bounds__(256) void mfma_gemm_qkv(
    const unsigned short* __restrict__ A,
    const unsigned short* __restrict__ Bt,
    unsigned short* __restrict__ qh,
    unsigned short* __restrict__ kh,
    unsigned short* __restrict__ vt)
{
    __shared__ unsigned short As[128*64];
    __shared__ unsigned short Bs[128*64];
    const int tid = threadIdx.x;
    const int w = tid >> 6, l = tid & 63;
    const int wr = w >> 1, wc = w & 1;
    const long m0 = (long)blockIdx.y * 128;
    const long n0 = (long)blockIdx.x * 128;
    const int srow = l >> 3;
    const int scol = (l & 7) << 3;
    const unsigned short* Ab = A + m0*CDIM;
    const unsigned short* Bb = Bt + n0*CDIM;
    const int fr = l & 15;
    const int fk = (l >> 4) << 3;

    f32x4 acc[4][4];
    #pragma unroll
    for (int m = 0; m < 4; m++)
        #pragma unroll
        for (int n = 0; n < 4; n++) acc[m][n] = (f32x4)0.0f;

    for (int k0 = 0; k0 < CDIM; k0 += 64) {
        __syncthreads();
        #pragma unroll
        for (int i = 0; i < 4; i++) {
            int seg = w*4 + i;
            GLOAD16(Ab + (long)(seg*8 + srow)*CDIM + k0 + scol, As + seg*512);
            GLOAD16(Bb + (long)(seg*8 + srow)*CDIM + k0 + scol, Bs + seg*512);
        }
        __syncthreads();
        #pragma unroll
        for (int kk = 0; kk < 2; kk++) {
            bf16x8 af[4], bf[4];
            #pragma unroll
            for (int m = 0; m < 4; m++)
                af[m] = *(const bf16x8*)&As[(wr*64 + m*16 + fr)*64 + kk*32 + fk];
            #pragma unroll
            for (int n = 0; n < 4; n++)
                bf[n] = *(const bf16x8*)&Bs[(wc*64 + n*16 + fr)*64 + kk*32 + fk];
            #pragma unroll
            for (int m = 0; m < 4; m++)
                #pragma unroll
                for (int n = 0; n < 4; n++)
                    acc[m][n] = __builtin_amdgcn_mfma_f32_16x16x32_bf16(
                        af[m], bf[n], acc[m][n], 0, 0, 0);
        }
    }

    const int rg = (l >> 4) << 2;
    #pragma unroll
    for (int n = 0; n < 4; n++) {
        int gn = (int)(n0 + wc*64 + n*16 + fr);
        int which = gn >> 9, hh = (gn >> 6) & 7, d = gn & 63;
        #pragma unroll
        for (int m = 0; m < 4; m++) {
            #pragma unroll
            for (int r = 0; r < 4; r++) {
                int gm = (int)(m0 + wr*64 + m*16 + rg + r);
                int b = gm >> 11, t = gm & (TT-1);
                int head = b*NH + hh;
                unsigned short val = f2bf(acc[m][n][r]);
                if (which == 0)      qh[((long)head*TT + t)*HS + d] = val;
                else if (which == 1) kh[((long)head*TT + t)*HS + d] = val;
                else                 vt[((long)head*HS + d)*TT + t] = val;
            }
        }
    }
}

// ---------------------------------------------------------------------------
// MFMA flash attention, split-KV=2. grid (TT/128, NHEADS, 2). 4 waves x 32 rows.
// qh/kh: [head][t][64] bf16; vt: [head][64][t] bf16. No 1/sqrt(hs) scale.
// Writes UNNORMALIZED partial O (f32) + per-row (m,l) for the combine pass.
// ---------------------------------------------------------------------------
__global__ __launch_bounds__(256) void attn_part(
    const unsigned short* __restrict__ qh,
    const unsigned short* __restrict__ kh,
    const unsigned short* __restrict__ vt,
    float* __restrict__ oP, float* __restrict__ ml)
{
    __shared__ unsigned short Ks[2][64*64];
    __shared__ unsigned short Vts[2][64*64];
    __shared__ unsigned short Ps[4][32*72];
    const int tid = threadIdx.x;
    const int w = tid >> 6, l = tid & 63;
    const int fr = l & 15, g = l >> 4;
    const int head = blockIdx.y;
    const int sp = blockIdx.z;
    const int x = blockIdx.x;
    const int qt0 = x * 128;
    const int qw = qt0 + w*32;
    const unsigned short* Qb = qh + (long)head*TT*HS;
    const unsigned short* Kb = kh + (long)head*TT*HS;
    const unsigned short* Vb = vt + (long)head*HS*TT;

    // Q fragments (A-layout)
    bf16x8 aq[2][2];
    #pragma unroll
    for (int mt = 0; mt < 2; mt++)
        #pragma unroll
        for (int ks = 0; ks < 2; ks++)
            aq[mt][ks] = *(const bf16x8*)&Qb[(long)(qw + mt*16 + fr)*HS + ks*32 + g*8];

    f32x4 acc_o[2][4];
    float mrun[2][4], lsum[2][4];
    #pragma unroll
    for (int mt = 0; mt < 2; mt++) {
        #pragma unroll
        for (int r = 0; r < 4; r++) { mrun[mt][r] = -INFINITY; lsum[mt][r] = 0.f; }
        #pragma unroll
        for (int n = 0; n < 4; n++) acc_o[mt][n] = (f32x4)0.0f;
    }

    // split sp processes chunks [sp*(x+1), (sp+1)*(x+1))  (each x+1 chunks)
    const int cbeg = sp * (x + 1);
    const int cend = cbeg + (x + 1);
    const int srow = l >> 3;
    const int scol = ((l & 7) ^ (srow & 7)) << 3;     // inverse-swizzled global col

    auto stage = [&](int c) {
        int buf = c & 1;
        int s0_ = c*64;
        #pragma unroll
        for (int i = 0; i < 2; i++) {
            int rb = i*32 + w*8;
            GLOAD16(Kb + (long)(s0_ + rb + srow)*HS + scol, &Ks[buf][rb*64]);
            GLOAD16(Vb + (long)(rb + srow)*TT + s0_ + scol, &Vts[buf][rb*64]);
        }
    };

    stage(cbeg);
    for (int c = cbeg; c < cend; c++) {
        const int s0 = c*64;
        const int buf = c & 1;
        __syncthreads();                  // drains vmcnt: buf[c] staged
        if (c + 1 < cend) stage(c+1);
        if (s0 > qw + 31) continue;       // wave-uniform skip

        // --- S = Q K^T ---
        bf16x8 bk[4][2];
        #pragma unroll
        for (int n = 0; n < 4; n++)
            #pragma unroll
            for (int ks = 0; ks < 2; ks++) {
                int row = n*16 + fr;
                int u = (ks*4 + g) ^ (row & 7);
                bk[n][ks] = *(const bf16x8*)&Ks[buf][row*64 + u*8];
            }
        f32x4 sc[2][4];
        #pragma unroll
        for (int mt = 0; mt < 2; mt++)
            #pragma unroll
            for (int n = 0; n < 4; n++) sc[mt][n] = (f32x4)0.0f;
        #pragma unroll
        for (int ks = 0; ks < 2; ks++)
            #pragma unroll
            for (int mt = 0; mt < 2; mt++)
                #pragma unroll
                for (int n = 0; n < 4; n++)
                    sc[mt][n] = __builtin_amdgcn_mfma_f32_16x16x32_bf16(
                        aq[mt][ks], bk[n][ks], sc[mt][n], 0, 0, 0);

        // --- causal mask + online softmax ---
        #pragma unroll
        for (int mt = 0; mt < 2; mt++) {
            #pragma unroll
            for (int r = 0; r < 4; r++) {
                int q = qw + mt*16 + g*4 + r;
                float rmax = -INFINITY;
                #pragma unroll
                for (int n = 0; n < 4; n++) {
                    float v = sc[mt][n][r];
                    v = (s0 + n*16 + fr <= q) ? v : -INFINITY;
                    sc[mt][n][r] = v;
                    rmax = fmaxf(rmax, v);
                }
                #pragma unroll
                for (int off = 8; off >= 1; off >>= 1)
                    rmax = fmaxf(rmax, __shfl_xor(rmax, off));
                float mnew = fmaxf(mrun[mt][r], rmax);   // finite: every kept chunk has key <= q
                float scale = __expf(mrun[mt][r] - mnew);
                float ps = 0.f;
                #pragma unroll
                for (int n = 0; n < 4; n++) {
                    float p = __expf(sc[mt][n][r] - mnew);
                    sc[mt][n][r] = p;
                    ps += p;
                }
                #pragma unroll
                for (int off = 8; off >= 1; off >>= 1)
                    ps += __shfl_xor(ps, off);
                lsum[mt][r] = lsum[mt][r]*scale + ps;
                mrun[mt][r] = mnew;
                #pragma unroll
                for (int n = 0; n < 4; n++) acc_o[mt][n][r] *= scale;
            }
        }

        // --- P -> LDS (C-layout -> A-layout transpose) ---
        #pragma unroll
        for (int mt = 0; mt < 2; mt++)
            #pragma unroll
            for (int n = 0; n < 4; n++)
                #pragma unroll
                for (int r = 0; r < 4; r++)
                    Ps[w][(mt*16 + g*4 + r)*72 + n*16 + fr] = f2bf(sc[mt][n][r]);

        // --- O += P V ---
        bf16x8 ap[2][2], bv[4][2];
        #pragma unroll
        for (int mt = 0; mt < 2; mt++)
            #pragma unroll
            for (int ks = 0; ks < 2; ks++)
                ap[mt][ks] = *(const bf16x8*)&Ps[w][(mt*16 + fr)*72 + ks*32 + g*8];
        #pragma unroll
        for (int n = 0; n < 4; n++)
            #pragma unroll
            for (int ks = 0; ks < 2; ks++) {
                int row = n*16 + fr;
                int u = (ks*4 + g) ^ (row & 7);
                bv[n][ks] = *(const bf16x8*)&Vts[buf][row*64 + u*8];
            }
        #pragma unroll
        for (int ks = 0; ks < 2; ks++)
            #pragma unroll
            for (int mt = 0; mt < 2; mt++)
                #pragma unroll
                for (int n = 0; n < 4; n++)
                    acc_o[mt][n] = __builtin_amdgcn_mfma_f32_16x16x32_bf16(
                        ap[mt][ks], bv[n][ks], acc_o[mt][n], 0, 0, 0);
    }

    // store partials: O' f32 [head*2+sp][t][d], (m,l) pairs
    float* oB = oP + ((long)(head*2 + sp)*TT)*HS;
    float* mlB = ml + ((long)(head*2 + sp)*TT)*2;
    #pragma unroll
    for (int mt = 0; mt < 2; mt++) {
        #pragma unroll
        for (int n = 0; n < 4; n++)
            #pragma unroll
            for (int r = 0; r < 4; r++)
                oB[(long)(qw + mt*16 + g*4 + r)*HS + n*16 + fr] = acc_o[mt][n][r];
        if (fr == 0) {
            #pragma unroll
            for (int r = 0; r < 4; r++) {
                int t = qw + mt*16 + g*4 + r;
                mlB[t*2]     = mrun[mt][r];
                mlB[t*2 + 1] = lsum[mt][r];
            }
        }
    }
}

// combine: att[b,t,h*64+d] = (O0 e^{m0-M} + O1 e^{m1-M}) / (l0 e^{m0-M} + l1 e^{m1-M})
__global__ __launch_bounds__(256) void attn_combine(
    const float* __restrict__ oP, const float* __restrict__ ml,
    unsigned short* __restrict__ att)
{
    const int gid = blockIdx.x*4 + (threadIdx.x >> 6);   // head*TT + t
    const int lane = threadIdx.x & 63;
    const int head = gid >> 11, t = gid & (TT-1);
    const int b = head >> 3, hh = head & 7;
    const long i0 = (long)(head*2 + 0)*TT + t;
    const long i1 = (long)(head*2 + 1)*TT + t;
    const float m0 = ml[i0*2], l0 = ml[i0*2+1];
    const float m1 = ml[i1*2], l1 = ml[i1*2+1];
    const float M = fmaxf(m0, m1);
    const float e0 = __expf(m0 - M), e1 = __expf(m1 - M);
    const float L = l0*e0 + l1*e1;
    const float v = (oP[i0*HS + lane]*e0 + oP[i1*HS + lane]*e1) / L;
    att[((long)b*TT + t)*CDIM + hh*HS + lane] = f2bf(v);
}

// ---------------------------------------------------------------------------
// Weight prep: f32 [R][Cn] -> bf16 [Cn][R], batched via grid.z
// ---------------------------------------------------------------------------
__global__ __launch_bounds__(256) void transpose_cast(
    const float* __restrict__ in, unsigned short* __restrict__ out,
    int R, int Cn, long in_z1, long in_z2, long out_z1, long out_z2, int z2n)
{
    const int z = blockIdx.z;
    const int z1 = z / z2n, z2 = z % z2n;
    const float* ip = in + (long)z1*in_z1 + (long)z2*in_z2;
    unsigned short* op = out + (long)z1*out_z1 + (long)z2*out_z2;
    __shared__ float tile[32][33];
    const int tx = threadIdx.x & 31, ty = threadIdx.x >> 5;
    const long r0 = (long)blockIdx.y*32, c0 = (long)blockIdx.x*32;
    #pragma unroll
    for (int i = 0; i < 4; i++)
        tile[ty + i*8][tx] = ip[(r0 + ty + i*8)*Cn + c0 + tx];
    __syncthreads();
    #pragma unroll
    for (int i = 0; i < 4; i++)
        op[(c0 + ty + i*8)*R + r0 + tx] = f2bf(tile[tx][ty + i*8]);
}

__global__ __launch_bounds__(256) void cast_kernel(
    const float* __restrict__ in, unsigned short* __restrict__ out, long n)
{
    long i = ((long)blockIdx.x*256 + threadIdx.x) * 4;
    if (i >= n) return;
    float4 v = *(const float4*)(in + i);
    ushort4 u = make_ushort4(f2bf(v.x), f2bf(v.y), f2bf(v.z), f2bf(v.w));
    *(ushort4*)(out + i) = u;
}

// ---------------------------------------------------------------------------
__global__ void embed_kernel(const int* __restrict__ idx,
                             const float* __restrict__ tok,
                             const float* __restrict__ pos,
                             float* __restrict__ x)
{
    const int r = blockIdx.x;
    const int t = r & (TT-1);
    const long tr = idx[r];
    const float* te = tok + tr*CDIM;
    const float* pe = pos + (long)t*CDIM;
    float* xo = x + (long)r*CDIM;
    for (int c = threadIdx.x; c < CDIM; c += blockDim.x)
        xo[c] = te[c] + pe[c];
}

// MODE 1: outp bf16 = LN(in).  MODE 2: outp f32 += LN(in).
// MODE 3: outp f32 += LN(in) AND outp2 bf16 = result.
template<int MODE>
__global__ __launch_bounds__(256) void ln_kernel(
    const float* __restrict__ in, const float* __restrict__ g,
    const float* __restrict__ bb, void* __restrict__ outp,
    void* __restrict__ outp2)
{
    const int wave = threadIdx.x >> 6;
    const int lane = threadIdx.x & 63;
    const long r = (long)blockIdx.x*4 + wave;
    const float* xr = in + r*CDIM;
    float vals[8];
    float s = 0.f;
    #pragma unroll
    for (int i = 0; i < 8; i++) { vals[i] = xr[lane + i*64]; s += vals[i]; }
    #pragma unroll
    for (int o = 32; o >= 1; o >>= 1) s += __shfl_xor(s, o);
    const float mean = s * (1.f/CDIM);
    float vs = 0.f;
    #pragma unroll
    for (int i = 0; i < 8; i++) { float d = vals[i]-mean; vs += d*d; }
    #pragma unroll
    for (int o = 32; o >= 1; o >>= 1) vs += __shfl_xor(vs, o);
    const float rstd = rsqrtf(vs*(1.f/CDIM) + 1e-5f);
    #pragma unroll
    for (int i = 0; i < 8; i++) {
        int c = lane + i*64;
        float nv = (vals[i]-mean)*rstd*g[c] + bb[c];
        if (MODE == 1) {
            ((unsigned short*)outp)[r*CDIM + c] = f2bf(nv);
        } else {
            float s2 = ((float*)outp)[r*CDIM + c] + nv;
            ((float*)outp)[r*CDIM + c] = s2;
            if (MODE == 3) ((unsigned short*)outp2)[r*CDIM + c] = f2bf(s2);
        }
    }
}

// ---------------------------------------------------------------------------
extern "C" void kernel_launch(void* const* d_in, const int* in_sizes, int n_in,
                              void* d_out, int out_size, void* d_ws, size_t ws_size,
                              hipStream_t stream)
{
    const int*   idx   = (const int*)  d_in[0];
    const float* tok   = (const float*)d_in[1];
    const float* pos   = (const float*)d_in[2];
    const float* ln1g  = (const float*)d_in[3];
    const float* ln1b  = (const float*)d_in[4];
    const float* wq    = (const float*)d_in[5];
    const float* wk    = (const float*)d_in[6];
    const float* wv    = (const float*)d_in[7];
    const float* projw = (const float*)d_in[8];
    const float* projb = (const float*)d_in[9];
    const float* ln2g  = (const float*)d_in[10];
    const float* ln2b  = (const float*)d_in[11];
    const float* ffw1  = (const float*)d_in[12];
    const float* ffb1  = (const float*)d_in[13];
    const float* ffw2  = (const float*)d_in[14];
    const float* ffb2  = (const float*)d_in[15];
    const float* flng  = (const float*)d_in[16];
    const float* flnb  = (const float*)d_in[17];
    const float* lmw   = (const float*)d_in[18];
    const float* lmb   = (const float*)d_in[19];
    float* out = (float*)d_out;

    // ---- workspace layout (~91.5 MB) ----
    char* wp = (char*)d_ws;
    float* x  = (float*)wp;           wp += (size_t)MROWS*CDIM*4;
    float* ff = (float*)wp;           wp += (size_t)MROWS*CDIM*4;
    unsigned short* h     = (unsigned short*)wp; wp += (size_t)MROWS*CDIM*2;
    unsigned short* lmt   = (unsigned short*)wp; wp += (size_t)VOCAB*CDIM*2;
    unsigned short* ff1t  = (unsigned short*)wp; wp += (size_t)NLAYER*4*CDIM*CDIM*2;
    unsigned short* ff2t  = (unsigned short*)wp; wp += (size_t)NLAYER*4*CDIM*CDIM*2;
    unsigned short* qkvt  = (unsigned short*)wp; wp += (size_t)NLAYER*QKVW*CDIM*2;
    unsigned short* projc = (unsigned short*)wp; wp += (size_t)NLAYER*CDIM*CDIM*2;
    unsigned short* qh    = (unsigned short*)wp; wp += (size_t)NHEADS*TT*HS*2;
    unsigned short* kh    = (unsigned short*)wp; wp += (size_t)NHEADS*TT*HS*2;
    unsigned short* vt    = (unsigned short*)wp; wp += (size_t)NHEADS*TT*HS*2;

    // ---- scratch in d_out (dead before LM-head GEMM fully overwrites it) ----
    unsigned short* f1  = (unsigned short*)d_out;          // [MROWS][2048] bf16, 16.8MB
    unsigned short* att = f1 + (size_t)MROWS*4*CDIM;       // [MROWS][512] bf16, 4.2MB
    float* oP = (float*)(att + (size_t)MROWS*CDIM);        // [NHEADS*2][TT][HS] f32, 16.8MB
    float* ml = oP + (size_t)NHEADS*2*TT*HS;               // [NHEADS*2][TT][2]  f32, 0.5MB

    // ---- weight prep (bf16, [N][K] panels) ----
    transpose_cast<<<dim3(VOCAB/32, CDIM/32, 1), 256, 0, stream>>>(
        lmw, lmt, CDIM, VOCAB, 0, 0, 0, 0, 1);
    transpose_cast<<<dim3(4*CDIM/32, CDIM/32, NLAYER), 256, 0, stream>>>(
        ffw1, ff1t, CDIM, 4*CDIM, (long)CDIM*4*CDIM, 0, (long)4*CDIM*CDIM, 0, 1);
    transpose_cast<<<dim3(CDIM/32, 4*CDIM/32, NLAYER), 256, 0, stream>>>(
        ffw2, ff2t, 4*CDIM, CDIM, (long)4*CDIM*CDIM, 0, (long)CDIM*4*CDIM, 0, 1);
    {
        const size_t QBLK = (size_t)CDIM * CDIM;   // 262144 elements
        transpose_cast<<<dim3(HS/32, CDIM/32, NLAYER*NH), 256, 0, stream>>>(
            wq, qkvt,            CDIM, HS,
            (long)NH*CDIM*HS, (long)CDIM*HS, (long)QKVW*CDIM, (long)HS*CDIM, NH);
        transpose_cast<<<dim3(HS/32, CDIM/32, NLAYER*NH), 256, 0, stream>>>(
            wk, qkvt + QBLK,     CDIM, HS,
            (long)NH*CDIM*HS, (long)CDIM*HS, (long)QKVW*CDIM, (long)HS*CDIM, NH);
        transpose_cast<<<dim3(HS/32, CDIM/32, NLAYER*NH), 256, 0, stream>>>(
            wv, qkvt + 2*QBLK,   CDIM, HS,
            (long)NH*CDIM*HS, (long)CDIM*HS, (long)QKVW*CDIM, (long)HS*CDIM, NH);
    }
    cast_kernel<<<(NLAYER*CDIM*CDIM/4 + 255)/256, 256, 0, stream>>>(
        projw, projc, (long)NLAYER*CDIM*CDIM);

    embed_kernel<<<MROWS, 256, 0, stream>>>(idx, tok, pos, x);

    for (int l = 0; l < NLAYER; l++) {
        const unsigned short* qkvt_l = qkvt + (size_t)l*QKVW*CDIM;
        const unsigned short* projc_l = projc + (size_t)l*CDIM*CDIM;
        const unsigned short* ff1t_l = ff1t + (size_t)l*4*CDIM*CDIM;
        const unsigned short* ff2t_l = ff2t + (size_t)l*4*CDIM*CDIM;

        ln_kernel<1><<<MROWS/4, 256, 0, stream>>>(x, ln1g + l*CDIM, ln1b + l*CDIM, h, nullptr);

        mfma_gemm_qkv<<<dim3(QKVW/128, MROWS/128), 256, 0, stream>>>(
            h, qkvt_l, qh, kh, vt);

        attn_part<<<dim3(TT/128, NHEADS, 2), 256, 0, stream>>>(qh, kh, vt, oP, ml);
        attn_combine<<<dim3(NHEADS*TT/4), 256, 0, stream>>>(oP, ml, att);

        mfma_gemm<5,false><<<dim3(CDIM/128, MROWS/128), 256, 0, stream>>>(
            att, CDIM, projc_l, CDIM, projb + l*CDIM, x, CDIM, x, CDIM);

        ln_kernel<1><<<MROWS/4, 256, 0, stream>>>(x, ln2g + l*CDIM, ln2b + l*CDIM, h, nullptr);

        mfma_gemm<3,true><<<dim3(4*CDIM/128, MROWS/128), 256, 0, stream>>>(
            h, CDIM, ff1t_l, CDIM, ffb1 + (size_t)l*4*CDIM, f1, 4*CDIM, nullptr, CDIM);

        mfma_gemm<1,false><<<dim3(CDIM/128, MROWS/128), 256, 0, stream>>>(
            f1, 4*CDIM, ff2t_l, 4*CDIM, ffb2 + l*CDIM, ff, CDIM, nullptr, 4*CDIM);

        if (l == NLAYER-1)
            ln_kernel<3><<<MROWS/4, 256, 0, stream>>>(ff, flng + l*CDIM, flnb + l*CDIM, x, h);
        else
            ln_kernel<2><<<MROWS/4, 256, 0, stream>>>(ff, flng + l*CDIM, flnb + l*CDIM, x, nullptr);
    }

    // LM head: out = x @ lm_w + lm_b   (h = bf16(x) fused into last ln)
    mfma_gemm<1,false><<<dim3(VOCAB/128, MROWS/128), 256, 0, stream>>>(
        h, CDIM, lmt, CDIM, lmb, out, VOCAB, nullptr, CDIM);
}